// Round 4
// baseline (86.844 us; speedup 1.0000x reference)
//
#include <hip/hip_runtime.h>

// Problem constants (B, N, D, H) from reference: (2, 1024, 128, 64)
#define Bb 2
#define Nn 1024
#define Dd 128
#define Hh 64

typedef float f32x2 __attribute__((ext_vector_type(2)));

// ---------------------------------------------------------------------------
// Kernel 1 (v3): P[b][h][n] = sum_d E[b,n,d]*W1[h,d] + b1[h]
//                Q[b][h][n] = sum_d E[b,n,d]*W1[h,128+d]
// Same structure as v2 (32o x 32n tiles, 256 blocks = all CUs, 4o x 1n
// per-thread micro-tile).  v3: accumulators as f32x2 pairs so the backend
// can emit v_pk_fma_f32 (pairs come free out of the ds_read_b128 of W;
// only the e-broadcast needs a splat, amortized over 2 pk_fma).
// ---------------------------------------------------------------------------
__global__ __launch_bounds__(256)
void k1_proj(const float* __restrict__ E, const float* __restrict__ W1,
             const float* __restrict__ b1, float* __restrict__ Pt,
             float* __restrict__ Qt) {
  __shared__ float El[32 * 132];   // [n][d], stride 132 (16B-aligned rows)
  __shared__ float Wl[128 * 36];   // [d][o], stride 36 (16B-aligned rows)

  const int t = threadIdx.x;
  const int oBase = blockIdx.x * 32;   // blocks 0,1 -> P rows; 2,3 -> Q rows
  const int nBase = blockIdx.y * 32;
  const int b = blockIdx.z;

  // Stage E tile (32 n x 128 d): coalesced float4 reads, b128 LDS writes.
  const float* esrc = E + ((size_t)b * Nn + nBase) * Dd;
  #pragma unroll
  for (int k = 0; k < 4; ++k) {
    int q = t + k * 256;
    int n = q >> 5;
    int c = (q & 31) << 2;
    float4 v = *(const float4*)(esrc + n * Dd + c);
    *(float4*)&El[n * 132 + c] = v;
  }
  // Stage W tile transposed: Wl[d][o].  Coalesced global rows of W1.
  #pragma unroll
  for (int k = 0; k < 16; ++k) {
    int q = t + k * 256;
    int o = q >> 7;         // 0..31 local
    int d = q & 127;
    int oG = oBase + o;
    int src = (oG < Hh) ? (oG * 2 * Dd + d) : ((oG - Hh) * 2 * Dd + Dd + d);
    Wl[d * 36 + o] = W1[src];
  }
  __syncthreads();

  const int to4 = (t & 7) << 2;   // o quad base (0,4,..,28)
  const int n   = t >> 3;         // node 0..31
  f32x2 acc01 = {0.f, 0.f}, acc23 = {0.f, 0.f};
  #pragma unroll 8
  for (int d = 0; d < 128; ++d) {
    const float  e  = El[n * 132 + d];            // 8-addr broadcast read
    const float4 w4 = *(const float4*)&Wl[d * 36 + to4];
    const f32x2 ev  = {e, e};
    const f32x2 w01 = {w4.x, w4.y};               // subreg pairs of the b128
    const f32x2 w23 = {w4.z, w4.w};
    acc01 += ev * w01;                            // -> v_pk_fma_f32
    acc23 += ev * w23;
  }

  const int oG = oBase + to4;     // wave-uniform P/Q side
  if (oG < Hh) {
    const float4 bias = *(const float4*)&b1[oG];
    float* dst = Pt + ((size_t)b * Hh + oG) * Nn + nBase + n;
    dst[0 * Nn] = acc01.x + bias.x;
    dst[1 * Nn] = acc01.y + bias.y;
    dst[2 * Nn] = acc23.x + bias.z;
    dst[3 * Nn] = acc23.y + bias.w;
  } else {
    float* dst = Qt + ((size_t)b * Hh + (oG - Hh)) * Nn + nBase + n;
    dst[0 * Nn] = acc01.x;
    dst[1 * Nn] = acc01.y;
    dst[2 * Nn] = acc23.x;
    dst[3 * Nn] = acc23.y;
  }
}

// ---------------------------------------------------------------------------
// Fused kernel 2+3 (v4): edge -> masked softmax, no intermediate matrix.
// Structure as round 3 (4 i-rows/block, 8 waves x 128-j slices, 2 blocks/CU
// = 4 waves/SIMD, Q direct from L2 with 2-deep register prefetch, softmax
// in registers + shuffles).
// v4: inner body packed over the ROW pair dimension so the backend can use
// VOP3P packed f32:
//   p-pairs {p0,p1},{p2,p3} fall directly out of the ds_read_b128 of Pl
//   (zero splat cost); q.x/q.y and w are splatted once per h and reused 4x.
//   Per h: 2 q-splats + 1 w-splat + 4x(pk_add + 2 v_max + pk_fma)
//        = ~19 issue slots vs 24 scalar.  relu stays scalar v_max on the
//   pair subregs (no v_pk_max_f32 on CDNA) — no repacking moves.
// If gfx950 packed-f32 is rate-neutral this is op-identical to v3 (no
// downside); if full-rate it cuts the dominant cost ~25%.
// ---------------------------------------------------------------------------
__global__ __launch_bounds__(512)
void k23_fused(const float* __restrict__ Pt, const float* __restrict__ Qt,
               const float* __restrict__ W2, const float* __restrict__ b2,
               const int* __restrict__ visited, float* __restrict__ out) {
  __shared__ float Pl[Hh][4];     // [h][r]  1 KB
  __shared__ float Ml[4][8];      // [row][wave] partial max
  __shared__ float Sl[4][8];      // [row][wave] partial sum

  const int t    = threadIdx.x;
  const int lane = t & 63;
  const int wv   = t >> 6;          // wave id = j-slice (0..7)
  const int iBase = blockIdx.x * 4;
  const int b    = blockIdx.y;

  // Stage P: 64 h x 4 rows (L2-hot strided gather, one element/thread).
  if (t < 256) {
    const int h = t >> 2, r = t & 3;
    Pl[h][r] = Pt[((size_t)b * Hh + h) * Nn + iBase + r];
  }
  __syncthreads();

  const int jOff = wv * 128 + lane * 2;
  const float* qbase = Qt + (size_t)b * Hh * Nn;   // wave-uniform base

  // acc[pair][j]: {row0,row1} and {row2,row3} pairs per j-column.
  f32x2 a01x = {0.f, 0.f}, a23x = {0.f, 0.f};
  f32x2 a01y = {0.f, 0.f}, a23y = {0.f, 0.f};

  // 2-deep register prefetch pipeline.
  f32x2 q0 = *(const f32x2*)(qbase + 0 * Nn + jOff);
  f32x2 q1 = *(const f32x2*)(qbase + 1 * Nn + jOff);
  #pragma unroll 8
  for (int h = 0; h < Hh; ++h) {
    const f32x2 q = (h & 1) ? q1 : q0;
    const float* qnext = qbase + (size_t)(h + 2) * Nn;  // uniform row base
    if (h & 1) q1 = *(const f32x2*)(qnext + jOff);      // h&1 static (unroll 8)
    else       q0 = *(const f32x2*)(qnext + jOff);

    const float  w  = W2[h];                       // uniform -> s_load
    const float4 p4 = *(const float4*)&Pl[h][0];   // single-addr broadcast
    const f32x2 p01 = {p4.x, p4.y};                // free subreg pairs
    const f32x2 p23 = {p4.z, p4.w};
    const f32x2 wv2 = {w, w};
    const f32x2 qx  = {q.x, q.x};
    const f32x2 qy  = {q.y, q.y};

    f32x2 t0 = p01 + qx;                           // v_pk_add_f32
    t0.x = fmaxf(t0.x, 0.f); t0.y = fmaxf(t0.y, 0.f);
    a01x += wv2 * t0;                              // v_pk_fma_f32
    f32x2 t1 = p23 + qx;
    t1.x = fmaxf(t1.x, 0.f); t1.y = fmaxf(t1.y, 0.f);
    a23x += wv2 * t1;
    f32x2 t2 = p01 + qy;
    t2.x = fmaxf(t2.x, 0.f); t2.y = fmaxf(t2.y, 0.f);
    a01y += wv2 * t2;
    f32x2 t3 = p23 + qy;
    t3.x = fmaxf(t3.x, 0.f); t3.y = fmaxf(t3.y, 0.f);
    a23y += wv2 * t3;
  }

  // Unpack to the [row][j] view for the epilogue.
  float acc[4][2];
  acc[0][0] = a01x.x; acc[1][0] = a01x.y; acc[2][0] = a23x.x; acc[3][0] = a23x.y;
  acc[0][1] = a01y.x; acc[1][1] = a01y.y; acc[2][1] = a23y.x; acc[3][1] = a23y.y;

  // ---- masked softmax (per-row: lane-local -> wave shuffle -> 8-way LDS) --
  const float NEG = -1000000000.0f;
  const float b2v = b2[0];
  const int vrow = b * Nn;

  bool vi[4];
  #pragma unroll
  for (int r = 0; r < 4; ++r) vi[r] = visited[vrow + iBase + r] != 0;

  const int2 vj = *(const int2*)(visited + vrow + jOff);
  const bool mj0 = vj.x != 0, mj1 = vj.y != 0;

  float vv[4][2];
  float m[4];
  #pragma unroll
  for (int r = 0; r < 4; ++r) {
    float x0 = (vi[r] | mj0) ? NEG : acc[r][0] + b2v;
    float x1 = (vi[r] | mj1) ? NEG : acc[r][1] + b2v;
    vv[r][0] = x0; vv[r][1] = x1;
    m[r] = fmaxf(x0, x1);
  }
  #pragma unroll
  for (int off = 32; off; off >>= 1)
    #pragma unroll
    for (int r = 0; r < 4; ++r)
      m[r] = fmaxf(m[r], __shfl_xor(m[r], off));
  if (lane == 0) {
    #pragma unroll
    for (int r = 0; r < 4; ++r) Ml[r][wv] = m[r];
  }
  __syncthreads();
  #pragma unroll
  for (int r = 0; r < 4; ++r) {
    const float4 a = *(const float4*)&Ml[r][0];
    const float4 c = *(const float4*)&Ml[r][4];
    m[r] = fmaxf(fmaxf(fmaxf(a.x, a.y), fmaxf(a.z, a.w)),
                 fmaxf(fmaxf(c.x, c.y), fmaxf(c.z, c.w)));
  }

  // All-masked row: every vv=NEG -> m=NEG -> exp(0)=1, sum=N -> uniform 1/N,
  // matching the reference exactly.
  float e[4][2];
  float s[4];
  #pragma unroll
  for (int r = 0; r < 4; ++r) {
    e[r][0] = __expf(vv[r][0] - m[r]);
    e[r][1] = __expf(vv[r][1] - m[r]);
    s[r] = e[r][0] + e[r][1];
  }
  #pragma unroll
  for (int off = 32; off; off >>= 1)
    #pragma unroll
    for (int r = 0; r < 4; ++r)
      s[r] += __shfl_xor(s[r], off);
  if (lane == 0) {
    #pragma unroll
    for (int r = 0; r < 4; ++r) Sl[r][wv] = s[r];
  }
  __syncthreads();
  #pragma unroll
  for (int r = 0; r < 4; ++r) {
    const float4 a = *(const float4*)&Sl[r][0];
    const float4 c = *(const float4*)&Sl[r][4];
    s[r] = ((a.x + a.y) + (a.z + a.w)) + ((c.x + c.y) + (c.z + c.w));
  }

  #pragma unroll
  for (int r = 0; r < 4; ++r) {
    const float inv = 1.0f / s[r];
    float* orow = out + ((size_t)(b * Nn + iBase + r)) * Nn + jOff;
    *(float2*)orow = make_float2(e[r][0] * inv, e[r][1] * inv);
  }
}

// ---------------------------------------------------------------------------
extern "C" void kernel_launch(void* const* d_in, const int* in_sizes, int n_in,
                              void* d_out, int out_size, void* d_ws, size_t ws_size,
                              hipStream_t stream) {
  const float* E       = (const float*)d_in[0];  // (B,N,D)
  const int*   visited = (const int*)d_in[1];    // (B,N) bool -> int32
  // d_in[2] remaining_capacity: unused by reference
  const float* W1      = (const float*)d_in[3];  // (H, 2D)
  const float* b1      = (const float*)d_in[4];  // (H,)
  const float* W2      = (const float*)d_in[5];  // (1, H)
  const float* b2      = (const float*)d_in[6];  // (1,)

  float* out = (float*)d_out;                    // (B,N,N)
  float* Pt  = (float*)d_ws;                     // B*H*N floats = 512 KB
  float* Qt  = (float*)((char*)d_ws + (size_t)Bb * Hh * Nn * sizeof(float));

  k1_proj<<<dim3(4, 32, Bb), 256, 0, stream>>>(E, W1, b1, Pt, Qt);
  k23_fused<<<dim3(Nn / 4, Bb), 512, 0, stream>>>(Pt, Qt, W2, b2, visited, out);
}